// Round 6
// baseline (296.064 us; speedup 1.0000x reference)
//
#include <hip/hip_runtime.h>
#include <hip/hip_bf16.h>

// Emformer attention, MI355X. Sizes fixed by the problem.
#define EMBED   1024
#define NHEADS  16
#define HDIM    64
#define U_LEN   2048
#define R_LEN   256
#define L_LEN   1024
#define M_LEN   512
#define Q_LEN   (U_LEN + R_LEN)                 // 2304
#define KV_LEN  (M_LEN + R_LEN + L_LEN + U_LEN) // 3840
#define X_ROWS  (M_LEN + R_LEN + U_LEN)         // 2816
#define NPART   6
#define KV_PART (KV_LEN / NPART)                // 640

typedef __attribute__((ext_vector_type(8))) short short8;
typedef __attribute__((ext_vector_type(4))) float f32x4;
typedef __attribute__((ext_vector_type(16))) float f32x16;

#define QSCALE 0.180336880f  /* 0.125 * log2(e): exp() via exp2(), implicit max=0 */

__device__ __forceinline__ void gl2lds16(const __hip_bfloat16* g, __hip_bfloat16* l) {
  __builtin_amdgcn_global_load_lds(
      (const __attribute__((address_space(1))) unsigned int*)g,
      (__attribute__((address_space(3))) unsigned int*)l, 16, 0, 0);
}

// bf16 round-to-nearest via +0x8000 bias (values >= 0 here; no NaN path)
__device__ __forceinline__ unsigned pack_bf16(float a, float b) {
  unsigned ua = __builtin_bit_cast(unsigned, a) + 0x8000u;
  unsigned ub = __builtin_bit_cast(unsigned, b) + 0x8000u;
  return (ua >> 16) | (ub & 0xFFFF0000u);
}

// ---------------------------------------------------------------- prep
// One kernel, block-range dispatched:
// [0,2816)      build X = bf16([memory; rc; utterance])
// [2816,3840)   Wq  -> WB rows 0..1023
// [3840,5888)   Wkv -> WB rows 1024..3071
// [5888,6912)   Wo  -> Wo_bf
// [6912,7936)   left-context insert (f32 key/value rows 768..1791 + bf16 K,V)
__global__ __launch_bounds__(256) void prep_kernel(
    const float* __restrict__ mem, const float* __restrict__ rc,
    const float* __restrict__ utt, const float* __restrict__ lk,
    const float* __restrict__ lv, const float* __restrict__ Wq,
    const float* __restrict__ Wkv, const float* __restrict__ Wo,
    __hip_bfloat16* __restrict__ X, __hip_bfloat16* __restrict__ WB,
    __hip_bfloat16* __restrict__ WoB,
    float* __restrict__ key_out, float* __restrict__ val_out,
    __hip_bfloat16* __restrict__ k_bf, __hip_bfloat16* __restrict__ v_bf) {
  int b = blockIdx.x, tid = threadIdx.x;
  if (b < 2816) {
    int row = b, col = tid * 4;
    const float* src;
    if (row < M_LEN)              src = mem + row * EMBED;
    else if (row < M_LEN + R_LEN) src = rc + (row - M_LEN) * EMBED;
    else                          src = utt + (row - M_LEN - R_LEN) * EMBED;
    float4 v = *reinterpret_cast<const float4*>(src + col);
    __hip_bfloat16* d = X + (size_t)row * EMBED + col;
    d[0] = __float2bfloat16(v.x); d[1] = __float2bfloat16(v.y);
    d[2] = __float2bfloat16(v.z); d[3] = __float2bfloat16(v.w);
  } else if (b < 6912) {
    const float* src; __hip_bfloat16* dst;
    int blk;
    if (b < 3840)      { src = Wq;  dst = WB;                blk = b - 2816; }
    else if (b < 5888) { src = Wkv; dst = WB + 1024 * 1024;  blk = b - 3840; }
    else               { src = Wo;  dst = WoB;               blk = b - 5888; }
    int idx = blk * 1024 + tid * 4;
    float4 v = *reinterpret_cast<const float4*>(src + idx);
    dst[idx + 0] = __float2bfloat16(v.x);
    dst[idx + 1] = __float2bfloat16(v.y);
    dst[idx + 2] = __float2bfloat16(v.z);
    dst[idx + 3] = __float2bfloat16(v.w);
  } else {
    int row = b - 6912, c0 = tid * 4;
    int orow = 768 + row;
    float4 kv4 = *reinterpret_cast<const float4*>(lk + row * EMBED + c0);
    float4 vv4 = *reinterpret_cast<const float4*>(lv + row * EMBED + c0);
    *reinterpret_cast<float4*>(key_out + (size_t)orow * EMBED + c0) = kv4;
    *reinterpret_cast<float4*>(val_out + (size_t)orow * EMBED + c0) = vv4;
    __hip_bfloat16* kd = k_bf + (size_t)orow * EMBED + c0;
    __hip_bfloat16* vd = v_bf + (size_t)orow * EMBED + c0;
    kd[0] = __float2bfloat16(kv4.x); kd[1] = __float2bfloat16(kv4.y);
    kd[2] = __float2bfloat16(kv4.z); kd[3] = __float2bfloat16(kv4.w);
    vd[0] = __float2bfloat16(vv4.x); vd[1] = __float2bfloat16(vv4.y);
    vd[2] = __float2bfloat16(vv4.z); vd[3] = __float2bfloat16(vv4.w);
  }
}

// v_bf [kv][d] -> vT [d][kv], 64x64 LDS tiles.
__global__ __launch_bounds__(256) void transpose_kernel(
    const unsigned short* __restrict__ v_bf, unsigned short* __restrict__ vT) {
  __shared__ unsigned short T[64][72];
  int kt = blockIdx.x * 64, d0 = blockIdx.y * 64;
  int t = threadIdx.x;
  int r = t >> 3, c = (t & 7) * 8;
#pragma unroll
  for (int half = 0; half < 2; half++) {
    int kv = r + half * 32;
    short8 v = *reinterpret_cast<const short8*>(v_bf + (size_t)(kt + kv) * EMBED + d0 + c);
#pragma unroll
    for (int j = 0; j < 8; j++) T[c + j][kv] = (unsigned short)v[j];
  }
  __syncthreads();
#pragma unroll
  for (int half = 0; half < 2; half++) {
    int d = r + half * 32;
    *reinterpret_cast<short8*>(vT + (size_t)(d0 + d) * KV_LEN + kt + c) =
        *reinterpret_cast<const short8*>(&T[d][c]);
  }
}

// ---------------------------------------------------------------- QKV GEMM
// C[2816,3072] = X @ [Wq;Wkv]^T + bias; 128x64 tile (MxN), BK=32, 4 waves
// (2x2, wave tile 64x32). Epilogue col routing:
//   [0,1024)    q_bf = bf16(C*QSCALE), rows >= 512 only (row - 512)
//   [1024,2048) key: orow remap, f32 key_out + bf16 k_bf
//   [2048,3072) value: orow remap, f32 val_out + bf16 v_bf
__global__ __launch_bounds__(256) void gemm_qkv(
    const __hip_bfloat16* __restrict__ A, const __hip_bfloat16* __restrict__ B,
    const float* __restrict__ bq, const float* __restrict__ bkv,
    float* __restrict__ key_out, float* __restrict__ val_out,
    __hip_bfloat16* __restrict__ q_bf, __hip_bfloat16* __restrict__ k_bf,
    __hip_bfloat16* __restrict__ v_bf) {
  __shared__ __align__(16) __hip_bfloat16 As[128 * 32];
  __shared__ __align__(16) __hip_bfloat16 Bs[64 * 32];
  const int K = EMBED;
  int tid = threadIdx.x;
  int wave = tid >> 6, lane = tid & 63, quad = lane >> 4, l16 = lane & 15;
  int wm = wave >> 1, wn = wave & 1;
  int mbase = blockIdx.y * 128, nbase = blockIdx.x * 64;

  if (nbase < 1024 && mbase + 128 <= 512) return;  // dead q rows

  const __hip_bfloat16* a0 = A + (size_t)(mbase + (tid >> 2)) * K + (tid & 3) * 8;
  const __hip_bfloat16* a1 = a0 + (size_t)64 * K;
  const __hip_bfloat16* b0 = B + (size_t)(nbase + (tid >> 2)) * K + (tid & 3) * 8;
  __hip_bfloat16* lA0 = As + tid * 8;
  __hip_bfloat16* lA1 = As + (tid + 256) * 8;
  __hip_bfloat16* lB0 = Bs + tid * 8;

  f32x4 acc[4][2] = {};
  for (int kt = 0; kt < K; kt += 32) {
    gl2lds16(a0 + kt, lA0);
    gl2lds16(a1 + kt, lA1);
    gl2lds16(b0 + kt, lB0);
    __syncthreads();
    short8 af[4], bfr[2];
#pragma unroll
    for (int i = 0; i < 4; i++)
      af[i] = *reinterpret_cast<const short8*>(As + (wm * 64 + i * 16 + l16) * 32 + quad * 8);
#pragma unroll
    for (int j = 0; j < 2; j++)
      bfr[j] = *reinterpret_cast<const short8*>(Bs + (wn * 32 + j * 16 + l16) * 32 + quad * 8);
#pragma unroll
    for (int i = 0; i < 4; i++)
#pragma unroll
      for (int j = 0; j < 2; j++)
        acc[i][j] = __builtin_amdgcn_mfma_f32_16x16x32_bf16(af[i], bfr[j], acc[i][j], 0, 0, 0);
    __syncthreads();
  }

#pragma unroll
  for (int i = 0; i < 4; i++) {
    int rb = mbase + wm * 64 + i * 16 + quad * 4;
#pragma unroll
    for (int j = 0; j < 2; j++) {
      int cg = nbase + wn * 32 + j * 16 + l16;
      float bv = (cg < 1024) ? bq[cg] : bkv[cg - 1024];
#pragma unroll
      for (int reg = 0; reg < 4; reg++) {
        int rg = rb + reg;
        float val = acc[i][j][reg] + bv;
        if (cg < 1024) {
          if (rg >= 512)
            q_bf[(size_t)(rg - 512) * 1024 + cg] = __float2bfloat16(val * QSCALE);
        } else {
          int orow = (rg < 768) ? rg : rg + 1024;
          if (cg < 2048) {
            int cc = cg - 1024;
            key_out[(size_t)orow * 1024 + cc] = val;
            k_bf[(size_t)orow * 1024 + cc] = __float2bfloat16(val);
          } else {
            int cc = cg - 2048;
            val_out[(size_t)orow * 1024 + cc] = val;
            v_bf[(size_t)orow * 1024 + cc] = __float2bfloat16(val);
          }
        }
      }
    }
  }
}

// ---------------------------------------------------------------- out GEMM
// partial[p][2304,1024] = attn @ Wo[kbase:kbase+512]^T; 64x64 tile, split-K x2,
// 4 waves (2x2, wave tile 32x32). Bias added in reduce.
__global__ __launch_bounds__(256) void gemm_out(
    const __hip_bfloat16* __restrict__ A, const __hip_bfloat16* __restrict__ B,
    float* __restrict__ partial) {
  __shared__ __align__(16) __hip_bfloat16 As[64 * 32];
  __shared__ __align__(16) __hip_bfloat16 Bs[64 * 32];
  const int K = EMBED, N = EMBED;
  int tid = threadIdx.x;
  int wave = tid >> 6, lane = tid & 63, quad = lane >> 4, l16 = lane & 15;
  int wm = wave >> 1, wn = wave & 1;
  int mbase = blockIdx.y * 64, nbase = blockIdx.x * 64;
  int kbase = blockIdx.z * 512;
  float* outp = partial + (size_t)blockIdx.z * Q_LEN * EMBED;

  const __hip_bfloat16* a0 = A + (size_t)(mbase + (tid >> 2)) * K + kbase + (tid & 3) * 8;
  const __hip_bfloat16* b0 = B + (size_t)(nbase + (tid >> 2)) * K + kbase + (tid & 3) * 8;
  __hip_bfloat16* lA0 = As + tid * 8;
  __hip_bfloat16* lB0 = Bs + tid * 8;

  f32x4 acc[2][2] = {};
  for (int kt = 0; kt < 512; kt += 32) {
    gl2lds16(a0 + kt, lA0);
    gl2lds16(b0 + kt, lB0);
    __syncthreads();
    short8 af[2], bfr[2];
#pragma unroll
    for (int i = 0; i < 2; i++)
      af[i] = *reinterpret_cast<const short8*>(As + (wm * 32 + i * 16 + l16) * 32 + quad * 8);
#pragma unroll
    for (int j = 0; j < 2; j++)
      bfr[j] = *reinterpret_cast<const short8*>(Bs + (wn * 32 + j * 16 + l16) * 32 + quad * 8);
#pragma unroll
    for (int i = 0; i < 2; i++)
#pragma unroll
      for (int j = 0; j < 2; j++)
        acc[i][j] = __builtin_amdgcn_mfma_f32_16x16x32_bf16(af[i], bfr[j], acc[i][j], 0, 0, 0);
    __syncthreads();
  }

#pragma unroll
  for (int i = 0; i < 2; i++) {
    int rb = mbase + wm * 32 + i * 16 + quad * 4;
#pragma unroll
    for (int j = 0; j < 2; j++) {
      int cg = nbase + wn * 32 + j * 16 + l16;
#pragma unroll
      for (int reg = 0; reg < 4; reg++)
        outp[(size_t)(rb + reg) * N + cg] = acc[i][j][reg];
    }
  }
}

// out = partial0 + partial1 + bias
__global__ __launch_bounds__(256) void reduce_out_kernel(
    const float* __restrict__ partial, const float* __restrict__ bias,
    float* __restrict__ outf) {
  int row = blockIdx.x, c = threadIdx.x * 4;
  float4 p0 = *reinterpret_cast<const float4*>(partial + (size_t)row * EMBED + c);
  float4 p1 = *reinterpret_cast<const float4*>(partial + (size_t)(Q_LEN + row) * EMBED + c);
  float4 bv = *reinterpret_cast<const float4*>(bias + c);
  float4 o;
  o.x = p0.x + p1.x + bv.x; o.y = p0.y + p1.y + bv.y;
  o.z = p0.z + p1.z + bv.z; o.w = p0.w + p1.w + bv.w;
  *reinterpret_cast<float4*>(outf + (size_t)row * EMBED + c) = o;
}

// ---------------------------------------------------------------- attention
// Flash, KV-split x6, no online max (scores in log2 units, sigma~0.6; f32
// exp2 overflow needs ~200 sigma; underflow->0 is correct softmax).
// Block: 4 waves, one head, 256 q (64 q/wave = 2 subtiles of 32).
// KV tile 64 via LDS, shared by all q: per wave-iter 16 ds_read_b128 feed
// 32 MFMAs (32x32x16). Q register-resident (B operand, 8 short8).
// S^T = mfma(K, Q): kv = (reg&3)+8*(reg>>2)+4*h2 + 32*kvs, q = lane&31.
// P stays in registers: PV B-fragments (kv = 16c+8*h2+j) assembled from the
// S^T C-layout via one shfl_xor(32) pair per chunk (half-lanes swap quads).
// O^T = mfma(V^T, P): d = (reg&3)+8*(reg>>2)+4*h2 + 32*ds, q = lane&31.
__global__ __launch_bounds__(256, 3) void attn_kernel(
    const __hip_bfloat16* __restrict__ q_bf, const __hip_bfloat16* __restrict__ k_bf,
    const __hip_bfloat16* __restrict__ vT,
    __hip_bfloat16* __restrict__ o_part, float* __restrict__ lsum) {
  __shared__ __align__(16) __hip_bfloat16 Ks[64][72];   // [kv][d]
  __shared__ __align__(16) __hip_bfloat16 VTs[64][72];  // [d][kv]
  int tid = threadIdx.x;
  int w = tid >> 6, lane = tid & 63, l31 = lane & 31, h2 = lane >> 5;
  int h = blockIdx.y, part = blockIdx.z;
  int qbase = blockIdx.x * 256;

  short8 Qf[2][4];
#pragma unroll
  for (int qs = 0; qs < 2; qs++)
#pragma unroll
    for (int ks = 0; ks < 4; ks++)
      Qf[qs][ks] = *reinterpret_cast<const short8*>(
          q_bf + (size_t)(qbase + w * 64 + qs * 32 + l31) * EMBED +
          h * HDIM + ks * 16 + h2 * 8);

  f32x16 ot[2][2] = {};
  float l_run[2] = {0.f, 0.f};

  int sr = tid >> 3, sc = (tid & 7) * 8;
  const int kv0 = part * KV_PART;

  for (int kt = kv0; kt < kv0 + KV_PART; kt += 64) {
#pragma unroll
    for (int half = 0; half < 2; half++) {
      int r = sr + half * 32;
      *reinterpret_cast<short8*>(&Ks[r][sc]) =
          *reinterpret_cast<const short8*>(k_bf + (size_t)(kt + r) * EMBED + h * HDIM + sc);
      *reinterpret_cast<short8*>(&VTs[r][sc]) =
          *reinterpret_cast<const short8*>(vT + (size_t)(h * HDIM + r) * KV_LEN + kt + sc);
    }
    __syncthreads();

#pragma unroll
    for (int kvs = 0; kvs < 2; kvs++) {
      short8 ak[4];
#pragma unroll
      for (int ks = 0; ks < 4; ks++)
        ak[ks] = *reinterpret_cast<const short8*>(&Ks[kvs * 32 + l31][ks * 16 + h2 * 8]);

      unsigned u[2][4][2];
#pragma unroll
      for (int qs = 0; qs < 2; qs++) {
        f32x16 s = {};
#pragma unroll
        for (int ks = 0; ks < 4; ks++)
          s = __builtin_amdgcn_mfma_f32_32x32x16_bf16(ak[ks], Qf[qs][ks], s, 0, 0, 0);
#pragma unroll
        for (int g = 0; g < 4; g++) {
          float p0 = exp2f(s[4 * g + 0]), p1 = exp2f(s[4 * g + 1]);
          float p2 = exp2f(s[4 * g + 2]), p3 = exp2f(s[4 * g + 3]);
          l_run[qs] += (p0 + p1) + (p2 + p3);
          u[qs][g][0] = pack_bf16(p0, p1);
          u[qs][g][1] = pack_bf16(p2, p3);
        }
      }

      // PV chunks c = 2*kvs + half (K=16 each)
#pragma unroll
      for (int half = 0; half < 2; half++) {
        int c = kvs * 2 + half;
        int gA = 2 * half, gB = 2 * half + 1;
        short8 av0 = *reinterpret_cast<const short8*>(&VTs[l31][c * 16 + h2 * 8]);
        short8 av1 = *reinterpret_cast<const short8*>(&VTs[32 + l31][c * 16 + h2 * 8]);
#pragma unroll
        for (int qs = 0; qs < 2; qs++) {
          unsigned s0 = h2 ? u[qs][gA][0] : u[qs][gB][0];
          unsigned s1 = h2 ? u[qs][gA][1] : u[qs][gB][1];
          unsigned r0 = __shfl_xor(s0, 32, 64);
          unsigned r1 = __shfl_xor(s1, 32, 64);
          uint4 fr;
          fr.x = h2 ? r0 : u[qs][gA][0];
          fr.y = h2 ? r1 : u[qs][gA][1];
          fr.z = h2 ? u[qs][gB][0] : r0;
          fr.w = h2 ? u[qs][gB][1] : r1;
          short8 pf = __builtin_bit_cast(short8, fr);
          ot[qs][0] = __builtin_amdgcn_mfma_f32_32x32x16_bf16(av0, pf, ot[qs][0], 0, 0, 0);
          ot[qs][1] = __builtin_amdgcn_mfma_f32_32x32x16_bf16(av1, pf, ot[qs][1], 0, 0, 0);
        }
      }
    }
    __syncthreads();
  }

#pragma unroll
  for (int qs = 0; qs < 2; qs++) {
    l_run[qs] += __shfl_xor(l_run[qs], 32, 64);
    float inv = 1.0f / l_run[qs];
    size_t orow = (size_t)part * Q_LEN + qbase + w * 64 + qs * 32 + l31;
#pragma unroll
    for (int ds = 0; ds < 2; ds++)
#pragma unroll
      for (int g = 0; g < 4; g++) {
        uint2 pk;
        pk.x = pack_bf16(ot[qs][ds][4 * g + 0] * inv, ot[qs][ds][4 * g + 1] * inv);
        pk.y = pack_bf16(ot[qs][ds][4 * g + 2] * inv, ot[qs][ds][4 * g + 3] * inv);
        *reinterpret_cast<uint2*>(
            o_part + orow * 1024 + h * HDIM + ds * 32 + g * 8 + h2 * 4) = pk;
      }
    if (lane < 32)
      lsum[orow * NHEADS + h] = l_run[qs];
  }
}

// merge KV partitions (shared implicit max=0): O = sum_p l_p*o_hat_p / sum l_p
__global__ __launch_bounds__(256) void merge_kernel(
    const __hip_bfloat16* __restrict__ o_part, const float* __restrict__ lsum,
    __hip_bfloat16* __restrict__ attn_bf) {
  int q = blockIdx.x;
  int c = threadIdx.x * 4;
  int h = c >> 6;
  float wt[NPART], L = 0.f;
#pragma unroll
  for (int p = 0; p < NPART; p++) {
    wt[p] = lsum[((size_t)p * Q_LEN + q) * NHEADS + h];
    L += wt[p];
  }
  float invL = 1.0f / L;
  float acc[4] = {0.f, 0.f, 0.f, 0.f};
#pragma unroll
  for (int p = 0; p < NPART; p++) {
    __hip_bfloat16 v[4];
    *reinterpret_cast<uint2*>(v) =
        *reinterpret_cast<const uint2*>(o_part + ((size_t)p * Q_LEN + q) * 1024 + c);
#pragma unroll
    for (int j = 0; j < 4; j++) acc[j] += wt[p] * __bfloat162float(v[j]);
  }
  uint2 pk;
  pk.x = pack_bf16(acc[0] * invL, acc[1] * invL);
  pk.y = pack_bf16(acc[2] * invL, acc[3] * invL);
  *reinterpret_cast<uint2*>(attn_bf + (size_t)q * 1024 + c) = pk;
}

// ---------------------------------------------------------------- launch

extern "C" void kernel_launch(void* const* d_in, const int* in_sizes, int n_in,
                              void* d_out, int out_size, void* d_ws, size_t ws_size,
                              hipStream_t stream) {
  const float* utt = (const float*)d_in[0];
  const float* rc  = (const float*)d_in[1];
  const float* mem = (const float*)d_in[2];
  const float* lk  = (const float*)d_in[3];
  const float* lv  = (const float*)d_in[4];
  const float* Wq  = (const float*)d_in[5];
  const float* bq  = (const float*)d_in[6];
  const float* Wkv = (const float*)d_in[7];
  const float* bkv = (const float*)d_in[8];
  const float* Wo  = (const float*)d_in[9];
  const float* bo  = (const float*)d_in[10];

  float* out_f   = (float*)d_out;                  // [2304,1024]
  float* key_out = out_f + Q_LEN * EMBED;          // [3840,1024]
  float* val_out = key_out + KV_LEN * EMBED;       // [3840,1024]

  char* ws = (char*)d_ws;
  size_t off = 0;
  __hip_bfloat16* X_bf   = (__hip_bfloat16*)(ws + off); off += (size_t)X_ROWS * EMBED * 2;
  __hip_bfloat16* WB_bf  = (__hip_bfloat16*)(ws + off); off += (size_t)3 * EMBED * EMBED * 2; // [Wq;Wkv]
  __hip_bfloat16* Wo_bf  = (__hip_bfloat16*)(ws + off); off += (size_t)EMBED * EMBED * 2;
  __hip_bfloat16* q_bf   = (__hip_bfloat16*)(ws + off); off += (size_t)Q_LEN * EMBED * 2;
  __hip_bfloat16* k_bf   = (__hip_bfloat16*)(ws + off); off += (size_t)KV_LEN * EMBED * 2;
  __hip_bfloat16* vT_bf  = (__hip_bfloat16*)(ws + off); off += (size_t)EMBED * KV_LEN * 2;
  __hip_bfloat16* o_part = (__hip_bfloat16*)(ws + off); off += (size_t)NPART * Q_LEN * EMBED * 2;
  // aliases (lifetimes disjoint): attn_bf over X_bf (X dead after QKV GEMM);
  // lsum over WB_bf (dead after QKV GEMM); v_bf over o_part (v_bf dead after
  // transpose, which runs before attn writes o_part); out-GEMM split-K
  // partials (2 x 9.4 MB f32) over q_bf/k_bf/vT_bf (all dead after attn).
  __hip_bfloat16* attn_bf = X_bf;
  float* lsum = (float*)WB_bf;
  __hip_bfloat16* v_bf = o_part;
  float* out_partial = (float*)q_bf;   // 18.9 MB spanning q_bf+k_bf+vT_bf (20.4 MB)
  (void)off; (void)ws_size; (void)in_sizes; (void)n_in; (void)out_size;

  prep_kernel<<<7936, 256, 0, stream>>>(mem, rc, utt, lk, lv, Wq, Wkv, Wo,
                                        X_bf, WB_bf, Wo_bf,
                                        key_out, val_out, k_bf, v_bf);
  gemm_qkv<<<dim3(3 * EMBED / 64, X_ROWS / 128), 256, 0, stream>>>(
      X_bf, WB_bf, bq, bkv, key_out, val_out, q_bf, k_bf, v_bf);
  transpose_kernel<<<dim3(KV_LEN / 64, EMBED / 64), 256, 0, stream>>>(
      (const unsigned short*)v_bf, (unsigned short*)vT_bf);
  attn_kernel<<<dim3(Q_LEN / 256, NHEADS, NPART), 256, 0, stream>>>(
      q_bf, k_bf, vT_bf, o_part, lsum);
  merge_kernel<<<Q_LEN, 256, 0, stream>>>(o_part, lsum, attn_bf);
  gemm_out<<<dim3(EMBED / 64, Q_LEN / 64, 2), 256, 0, stream>>>(
      attn_bf, Wo_bf, out_partial);
  reduce_out_kernel<<<Q_LEN, 256, 0, stream>>>(out_partial, bo, out_f);
}

// Round 7
// 237.739 us; speedup vs baseline: 1.2453x; 1.2453x over previous
//
#include <hip/hip_runtime.h>
#include <hip/hip_bf16.h>

// Emformer attention, MI355X. Sizes fixed by the problem.
#define EMBED   1024
#define NHEADS  16
#define HDIM    64
#define U_LEN   2048
#define R_LEN   256
#define L_LEN   1024
#define M_LEN   512
#define Q_LEN   (U_LEN + R_LEN)                 // 2304
#define KV_LEN  (M_LEN + R_LEN + L_LEN + U_LEN) // 3840
#define X_ROWS  (M_LEN + R_LEN + U_LEN)         // 2816
#define NPART   6
#define KV_PART (KV_LEN / NPART)                // 640

typedef __attribute__((ext_vector_type(8))) short short8;
typedef __attribute__((ext_vector_type(4))) float f32x4;
typedef __attribute__((ext_vector_type(16))) float f32x16;

#define QSCALE 0.180336880f  /* 0.125 * log2(e): exp() via exp2(), implicit max=0 */

__device__ __forceinline__ void gl2lds16(const __hip_bfloat16* g, __hip_bfloat16* l) {
  __builtin_amdgcn_global_load_lds(
      (const __attribute__((address_space(1))) unsigned int*)g,
      (__attribute__((address_space(3))) unsigned int*)l, 16, 0, 0);
}

// bf16 round-to-nearest via +0x8000 bias (values >= 0 here; no NaN path)
__device__ __forceinline__ unsigned pack_bf16(float a, float b) {
  unsigned ua = __builtin_bit_cast(unsigned, a) + 0x8000u;
  unsigned ub = __builtin_bit_cast(unsigned, b) + 0x8000u;
  return (ua >> 16) | (ub & 0xFFFF0000u);
}

// ---------------------------------------------------------------- prep
// One kernel, block-range dispatched:
// [0,2816)      build X = bf16([memory; rc; utterance])
// [2816,3840)   Wq  -> WB rows 0..1023
// [3840,5888)   Wkv -> WB rows 1024..3071
// [5888,6912)   Wo  -> Wo_bf
// [6912,7936)   left-context insert (f32 key/value rows 768..1791 + bf16 K,V)
__global__ __launch_bounds__(256) void prep_kernel(
    const float* __restrict__ mem, const float* __restrict__ rc,
    const float* __restrict__ utt, const float* __restrict__ lk,
    const float* __restrict__ lv, const float* __restrict__ Wq,
    const float* __restrict__ Wkv, const float* __restrict__ Wo,
    __hip_bfloat16* __restrict__ X, __hip_bfloat16* __restrict__ WB,
    __hip_bfloat16* __restrict__ WoB,
    float* __restrict__ key_out, float* __restrict__ val_out,
    __hip_bfloat16* __restrict__ k_bf, __hip_bfloat16* __restrict__ v_bf) {
  int b = blockIdx.x, tid = threadIdx.x;
  if (b < 2816) {
    int row = b, col = tid * 4;
    const float* src;
    if (row < M_LEN)              src = mem + row * EMBED;
    else if (row < M_LEN + R_LEN) src = rc + (row - M_LEN) * EMBED;
    else                          src = utt + (row - M_LEN - R_LEN) * EMBED;
    float4 v = *reinterpret_cast<const float4*>(src + col);
    __hip_bfloat16* d = X + (size_t)row * EMBED + col;
    d[0] = __float2bfloat16(v.x); d[1] = __float2bfloat16(v.y);
    d[2] = __float2bfloat16(v.z); d[3] = __float2bfloat16(v.w);
  } else if (b < 6912) {
    const float* src; __hip_bfloat16* dst;
    int blk;
    if (b < 3840)      { src = Wq;  dst = WB;                blk = b - 2816; }
    else if (b < 5888) { src = Wkv; dst = WB + 1024 * 1024;  blk = b - 3840; }
    else               { src = Wo;  dst = WoB;               blk = b - 5888; }
    int idx = blk * 1024 + tid * 4;
    float4 v = *reinterpret_cast<const float4*>(src + idx);
    dst[idx + 0] = __float2bfloat16(v.x);
    dst[idx + 1] = __float2bfloat16(v.y);
    dst[idx + 2] = __float2bfloat16(v.z);
    dst[idx + 3] = __float2bfloat16(v.w);
  } else {
    int row = b - 6912, c0 = tid * 4;
    int orow = 768 + row;
    float4 kv4 = *reinterpret_cast<const float4*>(lk + row * EMBED + c0);
    float4 vv4 = *reinterpret_cast<const float4*>(lv + row * EMBED + c0);
    *reinterpret_cast<float4*>(key_out + (size_t)orow * EMBED + c0) = kv4;
    *reinterpret_cast<float4*>(val_out + (size_t)orow * EMBED + c0) = vv4;
    __hip_bfloat16* kd = k_bf + (size_t)orow * EMBED + c0;
    __hip_bfloat16* vd = v_bf + (size_t)orow * EMBED + c0;
    kd[0] = __float2bfloat16(kv4.x); kd[1] = __float2bfloat16(kv4.y);
    kd[2] = __float2bfloat16(kv4.z); kd[3] = __float2bfloat16(kv4.w);
    vd[0] = __float2bfloat16(vv4.x); vd[1] = __float2bfloat16(vv4.y);
    vd[2] = __float2bfloat16(vv4.z); vd[3] = __float2bfloat16(vv4.w);
  }
}

// v_bf [kv][d] -> vT [d][kv], 64x64 LDS tiles.
__global__ __launch_bounds__(256) void transpose_kernel(
    const unsigned short* __restrict__ v_bf, unsigned short* __restrict__ vT) {
  __shared__ unsigned short T[64][72];
  int kt = blockIdx.x * 64, d0 = blockIdx.y * 64;
  int t = threadIdx.x;
  int r = t >> 3, c = (t & 7) * 8;
#pragma unroll
  for (int half = 0; half < 2; half++) {
    int kv = r + half * 32;
    short8 v = *reinterpret_cast<const short8*>(v_bf + (size_t)(kt + kv) * EMBED + d0 + c);
#pragma unroll
    for (int j = 0; j < 8; j++) T[c + j][kv] = (unsigned short)v[j];
  }
  __syncthreads();
#pragma unroll
  for (int half = 0; half < 2; half++) {
    int d = r + half * 32;
    *reinterpret_cast<short8*>(vT + (size_t)(d0 + d) * KV_LEN + kt + c) =
        *reinterpret_cast<const short8*>(&T[d][c]);
  }
}

// ---------------------------------------------------------------- QKV GEMM
// C[2816,3072] = X @ [Wq;Wkv]^T + bias; 128x64 tile (MxN), BK=64, 4 waves
// (2x2, wave tile 64x32). LDS rows are 64 elem (128 B); the 16B chunk index
// is XOR-swizzled by (row&7) to keep ds_read_b128 at 2-way banks. Since
// global_load_lds dest is lane-linear, the swizzle is applied to the GLOBAL
// source column (permutes within a 128 B row segment; coalescing intact).
// Epilogue col routing:
//   [0,1024)    q_bf = bf16(C*QSCALE), rows >= 512 only (row - 512)
//   [1024,2048) key: orow remap, f32 key_out + bf16 k_bf
//   [2048,3072) value: orow remap, f32 val_out + bf16 v_bf
__global__ __launch_bounds__(256) void gemm_qkv(
    const __hip_bfloat16* __restrict__ A, const __hip_bfloat16* __restrict__ B,
    const float* __restrict__ bq, const float* __restrict__ bkv,
    float* __restrict__ key_out, float* __restrict__ val_out,
    __hip_bfloat16* __restrict__ q_bf, __hip_bfloat16* __restrict__ k_bf,
    __hip_bfloat16* __restrict__ v_bf) {
  __shared__ __align__(16) __hip_bfloat16 As[128 * 64];  // 16 KB
  __shared__ __align__(16) __hip_bfloat16 Bs[64 * 64];   // 8 KB
  const int K = EMBED;
  int tid = threadIdx.x;
  int wave = tid >> 6, lane = tid & 63, quad = lane >> 4, l16 = lane & 15;
  int wm = wave >> 1, wn = wave & 1;
  int mbase = blockIdx.y * 128, nbase = blockIdx.x * 64;

  if (nbase < 1024 && mbase + 128 <= 512) return;  // dead q rows

  int srow = tid >> 3;                       // 0..31
  int scol = ((tid & 7) ^ (srow & 7)) * 8;   // swizzled source column (elem)
  const __hip_bfloat16* aG = A + (size_t)(mbase + srow) * K + scol;
  const __hip_bfloat16* bG = B + (size_t)(nbase + srow) * K + scol;
  int swz = l16 & 7;

  f32x4 acc[4][2] = {};
  for (int kt = 0; kt < K; kt += 64) {
    gl2lds16(aG + kt, As + tid * 8);
    gl2lds16(aG + (size_t)32 * K + kt, As + (tid + 256) * 8);
    gl2lds16(aG + (size_t)64 * K + kt, As + (tid + 512) * 8);
    gl2lds16(aG + (size_t)96 * K + kt, As + (tid + 768) * 8);
    gl2lds16(bG + kt, Bs + tid * 8);
    gl2lds16(bG + (size_t)32 * K + kt, Bs + (tid + 256) * 8);
    __syncthreads();
#pragma unroll
    for (int ks = 0; ks < 2; ks++) {
      short8 af[4], bfr[2];
#pragma unroll
      for (int i = 0; i < 4; i++)
        af[i] = *reinterpret_cast<const short8*>(
            As + (wm * 64 + i * 16 + l16) * 64 + ((ks * 4 + quad) ^ swz) * 8);
#pragma unroll
      for (int j = 0; j < 2; j++)
        bfr[j] = *reinterpret_cast<const short8*>(
            Bs + (wn * 32 + j * 16 + l16) * 64 + ((ks * 4 + quad) ^ swz) * 8);
#pragma unroll
      for (int i = 0; i < 4; i++)
#pragma unroll
        for (int j = 0; j < 2; j++)
          acc[i][j] = __builtin_amdgcn_mfma_f32_16x16x32_bf16(af[i], bfr[j], acc[i][j], 0, 0, 0);
    }
    __syncthreads();
  }

#pragma unroll
  for (int i = 0; i < 4; i++) {
    int rb = mbase + wm * 64 + i * 16 + quad * 4;
#pragma unroll
    for (int j = 0; j < 2; j++) {
      int cg = nbase + wn * 32 + j * 16 + l16;
      float bv = (cg < 1024) ? bq[cg] : bkv[cg - 1024];
#pragma unroll
      for (int reg = 0; reg < 4; reg++) {
        int rg = rb + reg;
        float val = acc[i][j][reg] + bv;
        if (cg < 1024) {
          if (rg >= 512)
            q_bf[(size_t)(rg - 512) * 1024 + cg] = __float2bfloat16(val * QSCALE);
        } else {
          int orow = (rg < 768) ? rg : rg + 1024;
          if (cg < 2048) {
            int cc = cg - 1024;
            key_out[(size_t)orow * 1024 + cc] = val;
            k_bf[(size_t)orow * 1024 + cc] = __float2bfloat16(val);
          } else {
            int cc = cg - 2048;
            val_out[(size_t)orow * 1024 + cc] = val;
            v_bf[(size_t)orow * 1024 + cc] = __float2bfloat16(val);
          }
        }
      }
    }
  }
}

// ---------------------------------------------------------------- out GEMM
// partial[p][2304,1024] = attn @ Wo[kbase:kbase+512]^T; 64x64 tile, BK=64,
// split-K x2, 4 waves (2x2, wave tile 32x32), same XOR swizzle as gemm_qkv.
// Bias added in reduce.
__global__ __launch_bounds__(256) void gemm_out(
    const __hip_bfloat16* __restrict__ A, const __hip_bfloat16* __restrict__ B,
    float* __restrict__ partial) {
  __shared__ __align__(16) __hip_bfloat16 As[64 * 64];
  __shared__ __align__(16) __hip_bfloat16 Bs[64 * 64];
  const int K = EMBED, N = EMBED;
  int tid = threadIdx.x;
  int wave = tid >> 6, lane = tid & 63, quad = lane >> 4, l16 = lane & 15;
  int wm = wave >> 1, wn = wave & 1;
  int mbase = blockIdx.y * 64, nbase = blockIdx.x * 64;
  int kbase = blockIdx.z * 512;
  float* outp = partial + (size_t)blockIdx.z * Q_LEN * EMBED;

  int srow = tid >> 3;
  int scol = ((tid & 7) ^ (srow & 7)) * 8;
  const __hip_bfloat16* aG = A + (size_t)(mbase + srow) * K + kbase + scol;
  const __hip_bfloat16* bG = B + (size_t)(nbase + srow) * K + kbase + scol;
  int swz = l16 & 7;

  f32x4 acc[2][2] = {};
  for (int kt = 0; kt < 512; kt += 64) {
    gl2lds16(aG + kt, As + tid * 8);
    gl2lds16(aG + (size_t)32 * K + kt, As + (tid + 256) * 8);
    gl2lds16(bG + kt, Bs + tid * 8);
    gl2lds16(bG + (size_t)32 * K + kt, Bs + (tid + 256) * 8);
    __syncthreads();
#pragma unroll
    for (int ks = 0; ks < 2; ks++) {
      short8 af[2], bfr[2];
#pragma unroll
      for (int i = 0; i < 2; i++)
        af[i] = *reinterpret_cast<const short8*>(
            As + (wm * 32 + i * 16 + l16) * 64 + ((ks * 4 + quad) ^ swz) * 8);
#pragma unroll
      for (int j = 0; j < 2; j++)
        bfr[j] = *reinterpret_cast<const short8*>(
            Bs + (wn * 32 + j * 16 + l16) * 64 + ((ks * 4 + quad) ^ swz) * 8);
#pragma unroll
      for (int i = 0; i < 2; i++)
#pragma unroll
        for (int j = 0; j < 2; j++)
          acc[i][j] = __builtin_amdgcn_mfma_f32_16x16x32_bf16(af[i], bfr[j], acc[i][j], 0, 0, 0);
    }
    __syncthreads();
  }

#pragma unroll
  for (int i = 0; i < 2; i++) {
    int rb = mbase + wm * 32 + i * 16 + quad * 4;
#pragma unroll
    for (int j = 0; j < 2; j++) {
      int cg = nbase + wn * 32 + j * 16 + l16;
#pragma unroll
      for (int reg = 0; reg < 4; reg++)
        outp[(size_t)(rb + reg) * N + cg] = acc[i][j][reg];
    }
  }
}

// out = partial0 + partial1 + bias
__global__ __launch_bounds__(256) void reduce_out_kernel(
    const float* __restrict__ partial, const float* __restrict__ bias,
    float* __restrict__ outf) {
  int row = blockIdx.x, c = threadIdx.x * 4;
  float4 p0 = *reinterpret_cast<const float4*>(partial + (size_t)row * EMBED + c);
  float4 p1 = *reinterpret_cast<const float4*>(partial + (size_t)(Q_LEN + row) * EMBED + c);
  float4 bv = *reinterpret_cast<const float4*>(bias + c);
  float4 o;
  o.x = p0.x + p1.x + bv.x; o.y = p0.y + p1.y + bv.y;
  o.z = p0.z + p1.z + bv.z; o.w = p0.w + p1.w + bv.w;
  *reinterpret_cast<float4*>(outf + (size_t)row * EMBED + c) = o;
}

// ---------------------------------------------------------------- attention
// (R5 kernel, verbatim — 64 q/wave in R6 spilled to scratch and regressed.)
// Flash, KV-split x6, no online max (scores in log2 units, sigma~0.6; f32
// exp2 overflow needs ~200 sigma; underflow->0 is correct softmax).
// Block: 4 waves, one head, 128 q (32 q/wave). KV tile 64 through LDS.
// 32x32x16 MFMAs, Q register-resident (B operand).
// S^T = mfma(K, Q): kv = (reg&3)+8*(reg>>2)+4*h2 + 32*kvs, q = lane&31.
// P never touches LDS: PV B-fragments (kv = 16c + 8*h2 + j) are assembled
// in-register from the S^T C-layout via one shfl_xor(32) pair per chunk.
// O^T = mfma(V^T, P): d = (reg&3)+8*(reg>>2)+4*h2 + 32*ds, q = lane&31.
__global__ __launch_bounds__(256, 4) void attn_kernel(
    const __hip_bfloat16* __restrict__ q_bf, const __hip_bfloat16* __restrict__ k_bf,
    const __hip_bfloat16* __restrict__ vT,
    __hip_bfloat16* __restrict__ o_part, float* __restrict__ lsum) {
  __shared__ __align__(16) __hip_bfloat16 Ks[64][72];   // [kv][d]
  __shared__ __align__(16) __hip_bfloat16 VTs[64][72];  // [d][kv]
  int tid = threadIdx.x;
  int w = tid >> 6, lane = tid & 63, l31 = lane & 31, h2 = lane >> 5;
  int h = blockIdx.y, part = blockIdx.z;
  int qbase = blockIdx.x * 128;
  int qg = qbase + w * 32 + l31;

  short8 Qf[4];
#pragma unroll
  for (int ks = 0; ks < 4; ks++)
    Qf[ks] = *reinterpret_cast<const short8*>(
        q_bf + (size_t)qg * EMBED + h * HDIM + ks * 16 + h2 * 8);

  f32x16 ot[2] = {};
  float l_run = 0.f;

  int sr = tid >> 3, sc = (tid & 7) * 8;
  const int kv0 = part * KV_PART;

  for (int kt = kv0; kt < kv0 + KV_PART; kt += 64) {
#pragma unroll
    for (int half = 0; half < 2; half++) {
      int r = sr + half * 32;
      *reinterpret_cast<short8*>(&Ks[r][sc]) =
          *reinterpret_cast<const short8*>(k_bf + (size_t)(kt + r) * EMBED + h * HDIM + sc);
      *reinterpret_cast<short8*>(&VTs[r][sc]) =
          *reinterpret_cast<const short8*>(vT + (size_t)(h * HDIM + r) * KV_LEN + kt + sc);
    }
    __syncthreads();

#pragma unroll
    for (int kvs = 0; kvs < 2; kvs++) {
      f32x16 s = {};
#pragma unroll
      for (int ks = 0; ks < 4; ks++) {
        short8 ak = *reinterpret_cast<const short8*>(&Ks[kvs * 32 + l31][ks * 16 + h2 * 8]);
        s = __builtin_amdgcn_mfma_f32_32x32x16_bf16(ak, Qf[ks], s, 0, 0, 0);
      }
      // exp2 + pack; group g holds kv = 32*kvs + 8g + 4*h2 + {0..3}
      unsigned u[4][2];
#pragma unroll
      for (int g = 0; g < 4; g++) {
        float p0 = exp2f(s[4 * g + 0]), p1 = exp2f(s[4 * g + 1]);
        float p2 = exp2f(s[4 * g + 2]), p3 = exp2f(s[4 * g + 3]);
        l_run += (p0 + p1) + (p2 + p3);
        u[g][0] = pack_bf16(p0, p1);
        u[g][1] = pack_bf16(p2, p3);
      }
      // PV chunks c = 2*kvs + half (K=16 each, kv range [16c,16c+16))
#pragma unroll
      for (int half = 0; half < 2; half++) {
        int c = kvs * 2 + half;
        int gA = 2 * half, gB = 2 * half + 1;
        unsigned s0 = h2 ? u[gA][0] : u[gB][0];
        unsigned s1 = h2 ? u[gA][1] : u[gB][1];
        unsigned r0 = __shfl_xor(s0, 32, 64);
        unsigned r1 = __shfl_xor(s1, 32, 64);
        uint4 fr;
        fr.x = h2 ? r0 : u[gA][0];
        fr.y = h2 ? r1 : u[gA][1];
        fr.z = h2 ? u[gB][0] : r0;
        fr.w = h2 ? u[gB][1] : r1;
        short8 pf = __builtin_bit_cast(short8, fr);
#pragma unroll
        for (int ds = 0; ds < 2; ds++) {
          short8 av = *reinterpret_cast<const short8*>(&VTs[ds * 32 + l31][c * 16 + h2 * 8]);
          ot[ds] = __builtin_amdgcn_mfma_f32_32x32x16_bf16(av, pf, ot[ds], 0, 0, 0);
        }
      }
    }
    __syncthreads();
  }

  l_run += __shfl_xor(l_run, 32, 64);
  float inv = 1.0f / l_run;

  // O^T: d = (reg&3)+8*(reg>>2)+4*h2+32*ds, q = l31. 4 consecutive d per group.
  size_t orow = (size_t)part * Q_LEN + qg;
#pragma unroll
  for (int ds = 0; ds < 2; ds++)
#pragma unroll
    for (int g = 0; g < 4; g++) {
      uint2 pk;
      pk.x = pack_bf16(ot[ds][4 * g + 0] * inv, ot[ds][4 * g + 1] * inv);
      pk.y = pack_bf16(ot[ds][4 * g + 2] * inv, ot[ds][4 * g + 3] * inv);
      *reinterpret_cast<uint2*>(
          o_part + orow * 1024 + h * HDIM + ds * 32 + g * 8 + h2 * 4) = pk;
    }
  if (lane < 32)
    lsum[orow * NHEADS + h] = l_run;
}

// merge KV partitions (shared implicit max=0): O = sum_p l_p*o_hat_p / sum l_p
__global__ __launch_bounds__(256) void merge_kernel(
    const __hip_bfloat16* __restrict__ o_part, const float* __restrict__ lsum,
    __hip_bfloat16* __restrict__ attn_bf) {
  int q = blockIdx.x;
  int c = threadIdx.x * 4;
  int h = c >> 6;
  float wt[NPART], L = 0.f;
#pragma unroll
  for (int p = 0; p < NPART; p++) {
    wt[p] = lsum[((size_t)p * Q_LEN + q) * NHEADS + h];
    L += wt[p];
  }
  float invL = 1.0f / L;
  float acc[4] = {0.f, 0.f, 0.f, 0.f};
#pragma unroll
  for (int p = 0; p < NPART; p++) {
    __hip_bfloat16 v[4];
    *reinterpret_cast<uint2*>(v) =
        *reinterpret_cast<const uint2*>(o_part + ((size_t)p * Q_LEN + q) * 1024 + c);
#pragma unroll
    for (int j = 0; j < 4; j++) acc[j] += wt[p] * __bfloat162float(v[j]);
  }
  uint2 pk;
  pk.x = pack_bf16(acc[0] * invL, acc[1] * invL);
  pk.y = pack_bf16(acc[2] * invL, acc[3] * invL);
  *reinterpret_cast<uint2*>(attn_bf + (size_t)q * 1024 + c) = pk;
}

// ---------------------------------------------------------------- launch

extern "C" void kernel_launch(void* const* d_in, const int* in_sizes, int n_in,
                              void* d_out, int out_size, void* d_ws, size_t ws_size,
                              hipStream_t stream) {
  const float* utt = (const float*)d_in[0];
  const float* rc  = (const float*)d_in[1];
  const float* mem = (const float*)d_in[2];
  const float* lk  = (const float*)d_in[3];
  const float* lv  = (const float*)d_in[4];
  const float* Wq  = (const float*)d_in[5];
  const float* bq  = (const float*)d_in[6];
  const float* Wkv = (const float*)d_in[7];
  const float* bkv = (const float*)d_in[8];
  const float* Wo  = (const float*)d_in[9];
  const float* bo  = (const float*)d_in[10];

  float* out_f   = (float*)d_out;                  // [2304,1024]
  float* key_out = out_f + Q_LEN * EMBED;          // [3840,1024]
  float* val_out = key_out + KV_LEN * EMBED;       // [3840,1024]

  char* ws = (char*)d_ws;
  size_t off = 0;
  __hip_bfloat16* X_bf   = (__hip_bfloat16*)(ws + off); off += (size_t)X_ROWS * EMBED * 2;
  __hip_bfloat16* WB_bf  = (__hip_bfloat16*)(ws + off); off += (size_t)3 * EMBED * EMBED * 2; // [Wq;Wkv]
  __hip_bfloat16* Wo_bf  = (__hip_bfloat16*)(ws + off); off += (size_t)EMBED * EMBED * 2;
  __hip_bfloat16* q_bf   = (__hip_bfloat16*)(ws + off); off += (size_t)Q_LEN * EMBED * 2;
  __hip_bfloat16* k_bf   = (__hip_bfloat16*)(ws + off); off += (size_t)KV_LEN * EMBED * 2;
  __hip_bfloat16* vT_bf  = (__hip_bfloat16*)(ws + off); off += (size_t)EMBED * KV_LEN * 2;
  __hip_bfloat16* o_part = (__hip_bfloat16*)(ws + off); off += (size_t)NPART * Q_LEN * EMBED * 2;
  // aliases (lifetimes disjoint): attn_bf over X_bf (X dead after QKV GEMM);
  // lsum over WB_bf (dead after QKV GEMM); v_bf over o_part (v_bf dead after
  // transpose, which runs before attn writes o_part); out-GEMM split-K
  // partials (2 x 9.4 MB f32) over q_bf/k_bf/vT_bf (all dead after attn).
  __hip_bfloat16* attn_bf = X_bf;
  float* lsum = (float*)WB_bf;
  __hip_bfloat16* v_bf = o_part;
  float* out_partial = (float*)q_bf;   // 18.9 MB spanning q_bf+k_bf+vT_bf (20.4 MB)
  (void)off; (void)ws_size; (void)in_sizes; (void)n_in; (void)out_size;

  prep_kernel<<<7936, 256, 0, stream>>>(mem, rc, utt, lk, lv, Wq, Wkv, Wo,
                                        X_bf, WB_bf, Wo_bf,
                                        key_out, val_out, k_bf, v_bf);
  gemm_qkv<<<dim3(3 * EMBED / 64, X_ROWS / 128), 256, 0, stream>>>(
      X_bf, WB_bf, bq, bkv, key_out, val_out, q_bf, k_bf, v_bf);
  transpose_kernel<<<dim3(KV_LEN / 64, EMBED / 64), 256, 0, stream>>>(
      (const unsigned short*)v_bf, (unsigned short*)vT_bf);
  attn_kernel<<<dim3(Q_LEN / 128, NHEADS, NPART), 256, 0, stream>>>(
      q_bf, k_bf, vT_bf, o_part, lsum);
  merge_kernel<<<Q_LEN, 256, 0, stream>>>(o_part, lsum, attn_bf);
  gemm_out<<<dim3(EMBED / 64, Q_LEN / 64, 2), 256, 0, stream>>>(
      attn_bf, Wo_bf, out_partial);
  reduce_out_kernel<<<Q_LEN, 256, 0, stream>>>(out_partial, bo, out_f);
}